// Round 1
// baseline (1302.650 us; speedup 1.0000x reference)
//
#include <hip/hip_runtime.h>
#include <math.h>

#define EPSF 1e-7f
#define MAXN 10.0f

__device__ __forceinline__ float sinh_div_f(float d) {      // sinh(d)/d with ref semantics
    float ds = fmaxf(d, 1e-6f);
    return (d < 1e-6f) ? 1.0f : sinhf(ds) / ds;
}
__device__ __forceinline__ float div_sinh_f(float d) {      // d/sinh(d) with ref semantics
    float ds = fmaxf(d, 1e-6f);
    return (d < 1e-6f) ? 1.0f : ds / sinhf(ds);
}
__device__ __forceinline__ float wred(float v) {            // 64-lane sum
#pragma unroll
    for (int off = 32; off > 0; off >>= 1) v += __shfl_xor(v, off, 64);
    return v;
}

// ---------------- Kernel A: z_h -> t0 = logmap0(projx(expmap0(logmap0(z_h)))) ----------------
// rows of 256, one wave per row, 4 floats/lane
__global__ void prep_kernel(const float* __restrict__ z, float* __restrict__ t, int N) {
    int gw = (blockIdx.x * blockDim.x + threadIdx.x) >> 6;
    int lane = threadIdx.x & 63;
    if (gw >= N) return;
    float4 zv = reinterpret_cast<const float4*>(z + (size_t)gw * 256)[lane];
    float z0 = __shfl(zv.x, 0, 64);
    float x0 = fmaxf(z0, 1.f + EPSF);
    float d = acoshf(x0);
    float f = div_sinh_f(d);
    float vx = (lane == 0) ? 0.f : zv.x * f;
    float vy = zv.y * f, vz = zv.z * f, vw = zv.w * f;
    float ss = wred(vx * vx + vy * vy + vz * vz + vw * vw);
    float n = sqrtf(ss);
    float s = fminf(1.f, MAXN / fmaxf(n, EPSF));
    float4 o;
    o.x = vx * s; o.y = vy * s; o.z = vz * s; o.w = vw * s;
    reinterpret_cast<float4*>(t + (size_t)gw * 256)[lane] = o;
}

// ---------------- collapse: y(row of 1024) -> [0, y_sp * min(1, 10/||y_sp||)] in place -------
__global__ void collapse_rows(float* __restrict__ y, int N) {
    int gw = (blockIdx.x * blockDim.x + threadIdx.x) >> 6;
    int lane = threadIdx.x & 63;
    if (gw >= N) return;
    float* r = y + (size_t)gw * 1024;
    float4 v[4];
    float ss = 0.f;
#pragma unroll
    for (int q = 0; q < 4; ++q) {
        v[q] = reinterpret_cast<const float4*>(r)[lane + 64 * q];
        float x = (q == 0 && lane == 0) ? 0.f : v[q].x;
        ss += x * x + v[q].y * v[q].y + v[q].z * v[q].z + v[q].w * v[q].w;
    }
    ss = wred(ss);
    float n = sqrtf(ss);
    float s = fminf(1.f, MAXN / fmaxf(n, EPSF));
#pragma unroll
    for (int q = 0; q < 4; ++q) {
        float4 o;
        o.x = v[q].x * s; o.y = v[q].y * s; o.z = v[q].z * s; o.w = v[q].w * s;
        if (q == 0 && lane == 0) o.x = 0.f;
        reinterpret_cast<float4*>(r)[lane + 64 * q] = o;
    }
}

// ---------------- f32 GEMM: C[N x M] = A[N x K] @ W[M x K]^T + bias ----------------
#define BM 128
#define BN 128
#define BKK 16
#define LDST 132

__global__ __launch_bounds__(256) void gemm_nt(const float* __restrict__ A,
                                               const float* __restrict__ W,
                                               const float* __restrict__ bias,
                                               float* __restrict__ C, int K, int M) {
    __shared__ __align__(16) float As[BKK][LDST];
    __shared__ __align__(16) float Bs[BKK][LDST];
    const int tid = threadIdx.x;
    const int tx = tid & 15, ty = tid >> 4;
    const int rowBase = blockIdx.y * BM;
    const int colBase = blockIdx.x * BN;
    float acc[8][8];
#pragma unroll
    for (int i = 0; i < 8; ++i)
#pragma unroll
        for (int j = 0; j < 8; ++j) acc[i][j] = 0.f;

    for (int k0 = 0; k0 < K; k0 += BKK) {
#pragma unroll
        for (int q = 0; q < 2; ++q) {
            int f = tid + q * 256;
            int m = f >> 2;
            int kq = (f & 3) << 2;
            const float4 va = *reinterpret_cast<const float4*>(A + (size_t)(rowBase + m) * K + k0 + kq);
            As[kq + 0][m] = va.x; As[kq + 1][m] = va.y; As[kq + 2][m] = va.z; As[kq + 3][m] = va.w;
            const float4 vb = *reinterpret_cast<const float4*>(W + (size_t)(colBase + m) * K + k0 + kq);
            Bs[kq + 0][m] = vb.x; Bs[kq + 1][m] = vb.y; Bs[kq + 2][m] = vb.z; Bs[kq + 3][m] = vb.w;
        }
        __syncthreads();
#pragma unroll
        for (int k = 0; k < BKK; ++k) {
            float a0[8], b0[8];
            *(float4*)&a0[0] = *(const float4*)&As[k][ty * 8];
            *(float4*)&a0[4] = *(const float4*)&As[k][ty * 8 + 4];
            *(float4*)&b0[0] = *(const float4*)&Bs[k][tx * 8];
            *(float4*)&b0[4] = *(const float4*)&Bs[k][tx * 8 + 4];
#pragma unroll
            for (int i = 0; i < 8; ++i)
#pragma unroll
                for (int j = 0; j < 8; ++j)
                    acc[i][j] = fmaf(a0[i], b0[j], acc[i][j]);
        }
        __syncthreads();
    }
#pragma unroll
    for (int i = 0; i < 8; ++i) {
        const size_t r = (size_t)(rowBase + ty * 8 + i);
#pragma unroll
        for (int j = 0; j < 8; j += 4) {
            const int c = colBase + tx * 8 + j;
            float4 v;
            v.x = acc[i][j + 0] + bias[c + 0];
            v.y = acc[i][j + 1] + bias[c + 1];
            v.z = acc[i][j + 2] + bias[c + 2];
            v.w = acc[i][j + 3] + bias[c + 3];
            *reinterpret_cast<float4*>(C + r * M + c) = v;
        }
    }
}

// ---------------- Kernel D: final Lorentz chain, rows of 256 ----------------
__global__ void final_kernel(const float* __restrict__ y2buf, const float* __restrict__ z,
                             const float* __restrict__ alpha_p, const float* __restrict__ step_p,
                             float* __restrict__ out, int N) {
    int gw = (blockIdx.x * blockDim.x + threadIdx.x) >> 6;
    int lane = threadIdx.x & 63;
    if (gw >= N) return;
    const bool l0 = (lane == 0);

    float4 yv = reinterpret_cast<const float4*>(y2buf + (size_t)gw * 256)[lane];
    float4 zv = reinterpret_cast<const float4*>(z + (size_t)gw * 256)[lane];
    float z0 = __shfl(zv.x, 0, 64);

    // v_transformed = logmap0(projx(expmap0(y2))) collapse, then v_final = step * it
    float yx = l0 ? 0.f : yv.x;
    float ss2 = wred(yx * yx + yv.y * yv.y + yv.z * yv.z + yv.w * yv.w);
    float n2 = sqrtf(ss2);
    float s2 = fminf(1.f, MAXN / fmaxf(n2, EPSF));
    float step = 1.f / (1.f + expf(-step_p[0]));
    float k1 = s2 * step;
    float vfx = yx * k1, vfy = yv.y * k1, vfz = yv.z * k1, vfw = yv.w * k1;

    // z_update = projx(safe_expmap(z, v_final)); v_final[0] == 0 exactly
    float r2 = wred(vfx * vfx + vfy * vfy + vfz * vfz + vfw * vfw);
    float n = sqrtf(fmaxf(r2, 0.f));
    float sc = fminf(1.f, MAXN / fmaxf(n, EPSF));
    float m = fminf(n, MAXN);
    float ch = coshf(m), sd = sinh_div_f(m);
    float ex = ch * zv.x + sd * sc * vfx;
    float ey = ch * zv.y + sd * sc * vfy;
    float ez = ch * zv.z + sd * sc * vfz;
    float ew = ch * zv.w + sd * sc * vfw;
    float exq = l0 ? 0.f : ex;
    float r3 = wred(exq * exq + ey * ey + ez * ez + ew * ew);
    float u0 = sqrtf(1.f + r3);   // projx'd first component of z_update

    // tangent_direction = logmap(z, z_update)
    float r4 = wred((l0 ? 0.f : zv.x * ex) + zv.y * ey + zv.z * ez + zv.w * ew);
    float ip = r4 - z0 * u0;
    ip = fminf(ip, -(1.f + EPSF));
    float dd = acoshf(-ip);
    float g = div_sinh_f(dd);
    float a = 1.f / (1.f + expf(-alpha_p[0]));
    float oa = (1.f - a) * g;
    float st0 = oa * (u0 + ip * z0);                      // component 0 (uniform)
    float stx = oa * (ex + ip * zv.x);                    // j>=1 (lane0 c0 unused)
    float sty = oa * (ey + ip * zv.y);
    float stz = oa * (ez + ip * zv.z);
    float stw = oa * (ew + ip * zv.w);
    float stxq = l0 ? 0.f : stx;

    // z_next = projx(safe_expmap(z, scaled_tangent)); general v (v0 != 0)
    float r5 = wred(stxq * stxq + sty * sty + stz * stz + stw * stw);
    float vv2 = r5 - st0 * st0;
    float n5 = sqrtf(fmaxf(vv2, 0.f));
    float s5 = fminf(1.f, MAXN / fmaxf(n5, EPSF));
    float m5 = fminf(n5, MAXN);
    float ch5 = coshf(m5), sd5 = sinh_div_f(m5);
    float fx = ch5 * zv.x + sd5 * s5 * stxq;              // lane0 c0 replaced below
    float fy = ch5 * zv.y + sd5 * s5 * sty;
    float fz = ch5 * zv.z + sd5 * s5 * stz;
    float fw = ch5 * zv.w + sd5 * s5 * stw;
    float fxq = l0 ? 0.f : fx;
    float r6 = wred(fxq * fxq + fy * fy + fz * fz + fw * fw);
    float zn0 = sqrtf(1.f + r6);
    if (l0) fx = zn0;

    float4 o;
    o.x = fx; o.y = fy; o.z = fz; o.w = fw;
    reinterpret_cast<float4*>(out + (size_t)gw * 256)[lane] = o;                  // z_next
    reinterpret_cast<float4*>(out + ((size_t)N + gw) * 256)[lane] = zv;           // z_h copy
}

extern "C" void kernel_launch(void* const* d_in, const int* in_sizes, int n_in,
                              void* d_out, int out_size, void* d_ws, size_t ws_size,
                              hipStream_t stream) {
    const float* z_h  = (const float*)d_in[0];
    const float* w0   = (const float*)d_in[1];
    const float* b0   = (const float*)d_in[2];
    const float* w1   = (const float*)d_in[3];
    const float* b1   = (const float*)d_in[4];
    const float* w2   = (const float*)d_in[5];
    const float* b2   = (const float*)d_in[6];
    const float* alph = (const float*)d_in[7];
    const float* stps = (const float*)d_in[8];
    float* out = (float*)d_out;

    const int D = 256, H = 1024;
    const int N = in_sizes[0] / D;   // 32768

    // scratch layout: first output slot doubles as t0 / y2 (overwritten by z_next at the end)
    float* t0 = out;                       // N x 256
    float* y0 = (float*)d_ws;              // N x 1024
    float* y1 = y0 + (size_t)N * H;        // N x 1024

    prep_kernel<<<N / 4, 256, 0, stream>>>(z_h, t0, N);
    gemm_nt<<<dim3(H / BN, N / BM), 256, 0, stream>>>(t0, w0, b0, y0, D, H);
    collapse_rows<<<N / 4, 256, 0, stream>>>(y0, N);
    gemm_nt<<<dim3(H / BN, N / BM), 256, 0, stream>>>(y0, w1, b1, y1, H, H);
    collapse_rows<<<N / 4, 256, 0, stream>>>(y1, N);
    gemm_nt<<<dim3(D / BN, N / BM), 256, 0, stream>>>(y1, w2, b2, t0, H, D);
    final_kernel<<<N / 4, 256, 0, stream>>>(t0, z_h, alph, stps, out, N);
}

// Round 2
// 539.952 us; speedup vs baseline: 2.4125x; 2.4125x over previous
//
#include <hip/hip_runtime.h>
#include <math.h>

#define EPSF 1e-7f
#define MAXN 10.0f

typedef unsigned short ushortT;
typedef __bf16 bf16_8 __attribute__((ext_vector_type(8)));
typedef float f32_4 __attribute__((ext_vector_type(4)));

__device__ __forceinline__ float sinh_div_f(float d) {
    float ds = fmaxf(d, 1e-6f);
    return (d < 1e-6f) ? 1.0f : sinhf(ds) / ds;
}
__device__ __forceinline__ float div_sinh_f(float d) {
    float ds = fmaxf(d, 1e-6f);
    return (d < 1e-6f) ? 1.0f : ds / sinhf(ds);
}
__device__ __forceinline__ float wred(float v) {
#pragma unroll
    for (int off = 32; off > 0; off >>= 1) v += __shfl_xor(v, off, 64);
    return v;
}
// f32 -> bf16(hi) + bf16(lo), both RNE
__device__ __forceinline__ void bsplit(float x, ushortT& h, ushortT& l) {
    unsigned u = __float_as_uint(x);
    unsigned r = (u + 0x7fffu + ((u >> 16) & 1u)) >> 16;
    h = (ushortT)r;
    float lo = x - __uint_as_float(r << 16);
    unsigned ul = __float_as_uint(lo);
    l = (ushortT)((ul + 0x7fffu + ((ul >> 16) & 1u)) >> 16);
}

__device__ __forceinline__ void gload_lds16(const void* g, void* l) {
    __builtin_amdgcn_global_load_lds(
        (const __attribute__((address_space(1))) unsigned int*)g,
        (__attribute__((address_space(3))) unsigned int*)l, 16, 0, 0);
}

// ---------------- weight split: f32 -> bf16 hi/lo planes ----------------
__global__ void split_kernel(const float* __restrict__ x, ushortT* __restrict__ hi,
                             ushortT* __restrict__ lo, int n4) {
    int idx = blockIdx.x * blockDim.x + threadIdx.x;
    if (idx >= n4) return;
    float4 v = reinterpret_cast<const float4*>(x)[idx];
    float f[4] = {v.x, v.y, v.z, v.w};
    ushortT hh[4], ll[4];
#pragma unroll
    for (int e = 0; e < 4; ++e) bsplit(f[e], hh[e], ll[e]);
    reinterpret_cast<ushort4*>(hi)[idx] = ushort4{hh[0], hh[1], hh[2], hh[3]};
    reinterpret_cast<ushort4*>(lo)[idx] = ushort4{ll[0], ll[1], ll[2], ll[3]};
}

// ---------------- prep: z_h -> clamped tangent t0 as bf16 hi/lo (rows of 256) ----------------
__global__ void prep_kernel(const float* __restrict__ z, ushortT* __restrict__ th,
                            ushortT* __restrict__ tl, int N) {
    int gw = (blockIdx.x * blockDim.x + threadIdx.x) >> 6;
    int lane = threadIdx.x & 63;
    if (gw >= N) return;
    float4 zv = reinterpret_cast<const float4*>(z + (size_t)gw * 256)[lane];
    float z0 = __shfl(zv.x, 0, 64);
    float x0 = fmaxf(z0, 1.f + EPSF);
    float d = acoshf(x0);
    float f = div_sinh_f(d);
    float vx = (lane == 0) ? 0.f : zv.x * f;
    float vy = zv.y * f, vz = zv.z * f, vw = zv.w * f;
    float ss = wred(vx * vx + vy * vy + vz * vz + vw * vw);
    float n = sqrtf(ss);
    float s = fminf(1.f, MAXN / fmaxf(n, EPSF));
    float o[4] = {vx * s, vy * s, vz * s, vw * s};
    ushortT hh[4], ll[4];
#pragma unroll
    for (int e = 0; e < 4; ++e) bsplit(o[e], hh[e], ll[e]);
    reinterpret_cast<ushort4*>(th + (size_t)gw * 256)[lane] = ushort4{hh[0], hh[1], hh[2], hh[3]};
    reinterpret_cast<ushort4*>(tl + (size_t)gw * 256)[lane] = ushort4{ll[0], ll[1], ll[2], ll[3]};
}

// ---------------- collapse: y f32 row(1024) -> [0, y_sp*min(1,10/||y_sp||)] as bf16 hi/lo ----
__global__ void collapse_rows(const float* __restrict__ y, ushortT* __restrict__ ph,
                              ushortT* __restrict__ pl, int N) {
    int gw = (blockIdx.x * blockDim.x + threadIdx.x) >> 6;
    int lane = threadIdx.x & 63;
    if (gw >= N) return;
    const float* r = y + (size_t)gw * 1024;
    float4 v[4];
    float ss = 0.f;
#pragma unroll
    for (int q = 0; q < 4; ++q) {
        v[q] = reinterpret_cast<const float4*>(r)[lane + 64 * q];
        float x = (q == 0 && lane == 0) ? 0.f : v[q].x;
        ss += x * x + v[q].y * v[q].y + v[q].z * v[q].z + v[q].w * v[q].w;
    }
    ss = wred(ss);
    float n = sqrtf(ss);
    float s = fminf(1.f, MAXN / fmaxf(n, EPSF));
#pragma unroll
    for (int q = 0; q < 4; ++q) {
        float o[4] = {v[q].x * s, v[q].y * s, v[q].z * s, v[q].w * s};
        if (q == 0 && lane == 0) o[0] = 0.f;
        ushortT hh[4], ll[4];
#pragma unroll
        for (int e = 0; e < 4; ++e) bsplit(o[e], hh[e], ll[e]);
        reinterpret_cast<ushort4*>(ph + (size_t)gw * 1024)[lane + 64 * q] = ushort4{hh[0], hh[1], hh[2], hh[3]};
        reinterpret_cast<ushort4*>(pl + (size_t)gw * 1024)[lane + 64 * q] = ushort4{ll[0], ll[1], ll[2], ll[3]};
    }
}

// ---------------- bf16 split-precision MFMA GEMM: C[N x M] = A @ W^T + bias ----------------
// A planes: [N][K] bf16 (hi/lo). W planes: [M][K] bf16 (hi/lo). C f32.
// 128x128 tile, BK=32, 4 waves each 64x64. XOR slot-swizzle (slot ^= (row>>1)&3),
// realized by pre-swizzling the per-lane GLOBAL source (global_load_lds writes linearly).
__global__ __launch_bounds__(256) void gemm_mfma(
    const ushortT* __restrict__ Ah, const ushortT* __restrict__ Al,
    const ushortT* __restrict__ Wh, const ushortT* __restrict__ Wl,
    const float* __restrict__ bias, float* __restrict__ C, int K, int M)
{
    __shared__ __align__(16) ushortT lds[4][128 * 32];  // Ah, Al, Bh, Bl planes
    const int tid = threadIdx.x;
    const int wid = tid >> 6;
    const int lane = tid & 63;
    const int rowBase = blockIdx.y * 128;
    const int colBase = blockIdx.x * 128;
    const int warpM = wid >> 1, warpN = wid & 1;

    f32_4 acc[4][4];
#pragma unroll
    for (int i = 0; i < 4; ++i)
#pragma unroll
        for (int j = 0; j < 4; ++j) acc[i][j] = f32_4{0.f, 0.f, 0.f, 0.f};

    // staging: wave w owns plane w. lane -> (row within chunk, 16B slot)
    const ushortT* planes[4] = {Ah, Al, Wh, Wl};
    const ushortT* src = planes[wid];
    const int sbase = (wid < 2) ? rowBase : colBase;
    const int srow = lane >> 2;   // 0..15
    const int sslot = lane & 3;   // physical 16B slot within 64B row

    const int frow = lane & 15;   // fragment row/col within 16
    const int fk = lane >> 4;     // logical k-slot (8 bf16 each)

    for (int k0 = 0; k0 < K; k0 += 32) {
#pragma unroll
        for (int j = 0; j < 8; ++j) {
            int row_p = j * 16 + srow;                  // 0..127 within tile
            int kslot = sslot ^ ((row_p >> 1) & 3);     // logical slot stored at phys sslot
            const ushortT* g = src + (size_t)(sbase + row_p) * K + k0 + kslot * 8;
            gload_lds16(g, &lds[wid][row_p * 32 + sslot * 8]);
        }
        __syncthreads();   // compiler drains vmcnt before s_barrier

        bf16_8 afh[4], afl[4], bfh[4], bfl[4];
#pragma unroll
        for (int i = 0; i < 4; ++i) {
            int ar = warpM * 64 + i * 16 + frow;
            int aks = fk ^ ((ar >> 1) & 3);
            afh[i] = *reinterpret_cast<const bf16_8*>(&lds[0][ar * 32 + aks * 8]);
            afl[i] = *reinterpret_cast<const bf16_8*>(&lds[1][ar * 32 + aks * 8]);
            int bc = warpN * 64 + i * 16 + frow;
            int bks = fk ^ ((bc >> 1) & 3);
            bfh[i] = *reinterpret_cast<const bf16_8*>(&lds[2][bc * 32 + bks * 8]);
            bfl[i] = *reinterpret_cast<const bf16_8*>(&lds[3][bc * 32 + bks * 8]);
        }
#pragma unroll
        for (int i = 0; i < 4; ++i)
#pragma unroll
            for (int j = 0; j < 4; ++j) {
                acc[i][j] = __builtin_amdgcn_mfma_f32_16x16x32_bf16(afh[i], bfh[j], acc[i][j], 0, 0, 0);
                acc[i][j] = __builtin_amdgcn_mfma_f32_16x16x32_bf16(afh[i], bfl[j], acc[i][j], 0, 0, 0);
                acc[i][j] = __builtin_amdgcn_mfma_f32_16x16x32_bf16(afl[i], bfh[j], acc[i][j], 0, 0, 0);
            }
        __syncthreads();   // before next overwrite of LDS
    }

#pragma unroll
    for (int i = 0; i < 4; ++i) {
        int row0 = rowBase + warpM * 64 + i * 16 + (lane >> 4) * 4;
#pragma unroll
        for (int j = 0; j < 4; ++j) {
            int col = colBase + warpN * 64 + j * 16 + (lane & 15);
            float bv = bias[col];
#pragma unroll
            for (int r = 0; r < 4; ++r)
                C[(size_t)(row0 + r) * M + col] = acc[i][j][r] + bv;
        }
    }
}

// ---------------- final Lorentz chain, rows of 256 ----------------
__global__ void final_kernel(const float* __restrict__ y2buf, const float* __restrict__ z,
                             const float* __restrict__ alpha_p, const float* __restrict__ step_p,
                             float* __restrict__ out, int N) {
    int gw = (blockIdx.x * blockDim.x + threadIdx.x) >> 6;
    int lane = threadIdx.x & 63;
    if (gw >= N) return;
    const bool l0 = (lane == 0);

    float4 yv = reinterpret_cast<const float4*>(y2buf + (size_t)gw * 256)[lane];
    float4 zv = reinterpret_cast<const float4*>(z + (size_t)gw * 256)[lane];
    float z0 = __shfl(zv.x, 0, 64);

    float yx = l0 ? 0.f : yv.x;
    float ss2 = wred(yx * yx + yv.y * yv.y + yv.z * yv.z + yv.w * yv.w);
    float n2 = sqrtf(ss2);
    float s2 = fminf(1.f, MAXN / fmaxf(n2, EPSF));
    float step = 1.f / (1.f + expf(-step_p[0]));
    float k1 = s2 * step;
    float vfx = yx * k1, vfy = yv.y * k1, vfz = yv.z * k1, vfw = yv.w * k1;

    float r2 = wred(vfx * vfx + vfy * vfy + vfz * vfz + vfw * vfw);
    float n = sqrtf(fmaxf(r2, 0.f));
    float sc = fminf(1.f, MAXN / fmaxf(n, EPSF));
    float m = fminf(n, MAXN);
    float ch = coshf(m), sd = sinh_div_f(m);
    float ex = ch * zv.x + sd * sc * vfx;
    float ey = ch * zv.y + sd * sc * vfy;
    float ez = ch * zv.z + sd * sc * vfz;
    float ew = ch * zv.w + sd * sc * vfw;
    float exq = l0 ? 0.f : ex;
    float r3 = wred(exq * exq + ey * ey + ez * ez + ew * ew);
    float u0 = sqrtf(1.f + r3);

    float r4 = wred((l0 ? 0.f : zv.x * ex) + zv.y * ey + zv.z * ez + zv.w * ew);
    float ip = r4 - z0 * u0;
    ip = fminf(ip, -(1.f + EPSF));
    float dd = acoshf(-ip);
    float g = div_sinh_f(dd);
    float a = 1.f / (1.f + expf(-alpha_p[0]));
    float oa = (1.f - a) * g;
    float st0 = oa * (u0 + ip * z0);
    float stx = oa * (ex + ip * zv.x);
    float sty = oa * (ey + ip * zv.y);
    float stz = oa * (ez + ip * zv.z);
    float stw = oa * (ew + ip * zv.w);
    float stxq = l0 ? 0.f : stx;

    float r5 = wred(stxq * stxq + sty * sty + stz * stz + stw * stw);
    float vv2 = r5 - st0 * st0;
    float n5 = sqrtf(fmaxf(vv2, 0.f));
    float s5 = fminf(1.f, MAXN / fmaxf(n5, EPSF));
    float m5 = fminf(n5, MAXN);
    float ch5 = coshf(m5), sd5 = sinh_div_f(m5);
    float fx = ch5 * zv.x + sd5 * s5 * stxq;
    float fy = ch5 * zv.y + sd5 * s5 * sty;
    float fz = ch5 * zv.z + sd5 * s5 * stz;
    float fw = ch5 * zv.w + sd5 * s5 * stw;
    float fxq = l0 ? 0.f : fx;
    float r6 = wred(fxq * fxq + fy * fy + fz * fz + fw * fw);
    float zn0 = sqrtf(1.f + r6);
    if (l0) fx = zn0;

    float4 o;
    o.x = fx; o.y = fy; o.z = fz; o.w = fw;
    reinterpret_cast<float4*>(out + (size_t)gw * 256)[lane] = o;
    reinterpret_cast<float4*>(out + ((size_t)N + gw) * 256)[lane] = zv;
}

extern "C" void kernel_launch(void* const* d_in, const int* in_sizes, int n_in,
                              void* d_out, int out_size, void* d_ws, size_t ws_size,
                              hipStream_t stream) {
    const float* z_h  = (const float*)d_in[0];
    const float* w0   = (const float*)d_in[1];
    const float* b0   = (const float*)d_in[2];
    const float* w1   = (const float*)d_in[3];
    const float* b1   = (const float*)d_in[4];
    const float* w2   = (const float*)d_in[5];
    const float* b2   = (const float*)d_in[6];
    const float* alph = (const float*)d_in[7];
    const float* stps = (const float*)d_in[8];
    float* out = (float*)d_out;

    const int D = 256, H = 1024;
    const int N = in_sizes[0] / D;   // 32768

    // d_ws (256 MB): y f32 buffer | act hi plane | act lo plane
    float*  bufF = (float*)d_ws;                                     // N x 1024 f32 (128 MB)
    ushortT* actH = (ushortT*)((char*)d_ws + (size_t)N * H * 4);     // N x 1024 bf16 (64 MB)
    ushortT* actL = actH + (size_t)N * H;                            // N x 1024 bf16 (64 MB)

    // weight hi/lo planes live in d_out's head; overwritten by final_kernel at the end
    ushortT* w0h = (ushortT*)d_out;
    ushortT* w0l = w0h + (size_t)H * D;
    ushortT* w1h = w0l + (size_t)H * D;
    ushortT* w1l = w1h + (size_t)H * H;
    ushortT* w2h = w1l + (size_t)H * H;
    ushortT* w2l = w2h + (size_t)D * H;   // ends ~6.3 MB into the 64 MB output buffer

    split_kernel<<<(H * D / 4 + 255) / 256, 256, 0, stream>>>(w0, w0h, w0l, H * D / 4);
    split_kernel<<<(H * H / 4 + 255) / 256, 256, 0, stream>>>(w1, w1h, w1l, H * H / 4);
    split_kernel<<<(D * H / 4 + 255) / 256, 256, 0, stream>>>(w2, w2h, w2l, D * H / 4);

    prep_kernel<<<N / 4, 256, 0, stream>>>(z_h, actH, actL, N);   // layer-0 planes, K=256
    gemm_mfma<<<dim3(H / 128, N / 128), 256, 0, stream>>>(actH, actL, w0h, w0l, b0, bufF, D, H);
    collapse_rows<<<N / 4, 256, 0, stream>>>(bufF, actH, actL, N);
    gemm_mfma<<<dim3(H / 128, N / 128), 256, 0, stream>>>(actH, actL, w1h, w1l, b1, bufF, H, H);
    collapse_rows<<<N / 4, 256, 0, stream>>>(bufF, actH, actL, N);
    gemm_mfma<<<dim3(D / 128, N / 128), 256, 0, stream>>>(actH, actL, w2h, w2l, b2, bufF, H, D);
    final_kernel<<<N / 4, 256, 0, stream>>>(bufF, z_h, alph, stps, out, N);
}

// Round 3
// 422.065 us; speedup vs baseline: 3.0864x; 1.2793x over previous
//
#include <hip/hip_runtime.h>
#include <math.h>

#define EPSF 1e-7f
#define MAXN 10.0f

typedef unsigned short ushortT;
typedef __bf16 bf16_8 __attribute__((ext_vector_type(8)));
typedef float f32_4 __attribute__((ext_vector_type(4)));

#define MFMA16 __builtin_amdgcn_mfma_f32_16x16x32_bf16

__device__ __forceinline__ float sinh_div_f(float d) {
    float ds = fmaxf(d, 1e-6f);
    return (d < 1e-6f) ? 1.0f : sinhf(ds) / ds;
}
__device__ __forceinline__ float div_sinh_f(float d) {
    float ds = fmaxf(d, 1e-6f);
    return (d < 1e-6f) ? 1.0f : ds / sinhf(ds);
}
__device__ __forceinline__ float wred(float v) {
#pragma unroll
    for (int off = 32; off > 0; off >>= 1) v += __shfl_xor(v, off, 64);
    return v;
}
// f32 -> bf16(hi) + bf16(lo), both RNE
__device__ __forceinline__ void bsplit(float x, ushortT& h, ushortT& l) {
    unsigned u = __float_as_uint(x);
    unsigned r = (u + 0x7fffu + ((u >> 16) & 1u)) >> 16;
    h = (ushortT)r;
    float lo = x - __uint_as_float(r << 16);
    unsigned ul = __float_as_uint(lo);
    l = (ushortT)((ul + 0x7fffu + ((ul >> 16) & 1u)) >> 16);
}
__device__ __forceinline__ void gload_lds16(const void* g, void* l) {
    __builtin_amdgcn_global_load_lds(
        (const __attribute__((address_space(1))) unsigned int*)g,
        (__attribute__((address_space(3))) unsigned int*)l, 16, 0, 0);
}

// ---------------- weight split ----------------
__global__ void split_kernel(const float* __restrict__ x, ushortT* __restrict__ hi,
                             ushortT* __restrict__ lo, int n4) {
    int idx = blockIdx.x * blockDim.x + threadIdx.x;
    if (idx >= n4) return;
    float4 v = reinterpret_cast<const float4*>(x)[idx];
    float f[4] = {v.x, v.y, v.z, v.w};
    ushortT hh[4], ll[4];
#pragma unroll
    for (int e = 0; e < 4; ++e) bsplit(f[e], hh[e], ll[e]);
    reinterpret_cast<ushort4*>(hi)[idx] = ushort4{hh[0], hh[1], hh[2], hh[3]};
    reinterpret_cast<ushort4*>(lo)[idx] = ushort4{ll[0], ll[1], ll[2], ll[3]};
}

// ---------------- prep: z_h -> SCALED clamped tangent planes (rows of 256) ----------------
__global__ void prep_kernel(const float* __restrict__ z, ushortT* __restrict__ th,
                            ushortT* __restrict__ tl, int N) {
    int gw = (blockIdx.x * blockDim.x + threadIdx.x) >> 6;
    int lane = threadIdx.x & 63;
    if (gw >= N) return;
    float4 zv = reinterpret_cast<const float4*>(z + (size_t)gw * 256)[lane];
    float z0 = __shfl(zv.x, 0, 64);
    float x0 = fmaxf(z0, 1.f + EPSF);
    float d = acoshf(x0);
    float f = div_sinh_f(d);
    float vx = (lane == 0) ? 0.f : zv.x * f;
    float vy = zv.y * f, vz = zv.z * f, vw = zv.w * f;
    float ss = wred(vx * vx + vy * vy + vz * vz + vw * vw);
    float n = sqrtf(ss);
    float s = fminf(1.f, MAXN / fmaxf(n, EPSF));
    float o[4] = {vx * s, vy * s, vz * s, vw * s};
    ushortT hh[4], ll[4];
#pragma unroll
    for (int e = 0; e < 4; ++e) bsplit(o[e], hh[e], ll[e]);
    reinterpret_cast<ushort4*>(th + (size_t)gw * 256)[lane] = ushort4{hh[0], hh[1], hh[2], hh[3]};
    reinterpret_cast<ushort4*>(tl + (size_t)gw * 256)[lane] = ushort4{ll[0], ll[1], ll[2], ll[3]};
}

// ---------------- row scale from partial sumsq ----------------
__global__ void rowscale_kernel(const float* __restrict__ partials, float* __restrict__ scale,
                                int N, int nSlices) {
    int r = blockIdx.x * blockDim.x + threadIdx.x;
    if (r >= N) return;
    float s = 0.f;
    for (int k = 0; k < nSlices; ++k) s += partials[(size_t)k * N + r];
    float n = sqrtf(s);
    scale[r] = fminf(1.f, MAXN / fmaxf(n, EPSF));
}

// ---------------- 3-phase counted-vmcnt split-bf16 GEMM ----------------
// C[N x M] = (sA_r * A) @ W^T + bias ; A planes [N][K], W planes [M][K], BM=256 BN=128 BK=32.
// LDS buffer (elems): Ah@0 (256x32), Al@8192, Bh@16384 (128x32), Bl@20480. x2 buffers.
// Staging rounds per tile (per-thread 16B each): r0=Ah0 r1=Ah1 r2=Bh r3=Bl r4=Al0 r5=Al1.
// Phase needs: P0(hi*hi): r0-r2; P1(hi*lo): r3; P2(lo*hi): r4,r5 -> vmcnt(5)/(6)/(6).
// OUTMODE 0: write bf16 hi/lo planes + partial row-sumsq. OUTMODE 1: write f32.
template<int OUTMODE>
__global__ __launch_bounds__(512, 1) void gemm_v3(
    const ushortT* __restrict__ Ah_g, const ushortT* __restrict__ Al_g,
    const ushortT* __restrict__ Wh_g, const ushortT* __restrict__ Wl_g,
    const float* __restrict__ bias, const float* __restrict__ scaleA,
    float* __restrict__ outF, ushortT* __restrict__ outH, ushortT* __restrict__ outL,
    float* __restrict__ partials, int K, int M, int nColBlk, int Nrows)
{
    __shared__ __align__(16) ushortT lds[2][24576];
    const int tid = threadIdx.x;
    const int wid = tid >> 6, lane = tid & 63;
    // bijective XCD swizzle (grid % 8 == 0), cols fastest within chunk -> A-panel L2 reuse
    const int nwg = gridDim.x;
    const int swz = ((int)blockIdx.x & 7) * (nwg >> 3) + ((int)blockIdx.x >> 3);
    const int rb = swz / nColBlk, cb = swz % nColBlk;
    const int rowBase = rb * 256, colBase = cb * 128;

    // staging source addressing (pre-swizzled so linear LDS dest gets swizzled slots)
    const int rl = tid >> 2;
    const int ks = (tid & 3) ^ ((rl >> 1) & 3);
    const ushortT* g0 = Ah_g + (size_t)(rowBase + rl) * K + ks * 8;
    const ushortT* g1 = Ah_g + (size_t)(rowBase + 128 + rl) * K + ks * 8;
    const ushortT* g2 = Wh_g + (size_t)(colBase + rl) * K + ks * 8;
    const ushortT* g3 = Wl_g + (size_t)(colBase + rl) * K + ks * 8;
    const ushortT* g4 = Al_g + (size_t)(rowBase + rl) * K + ks * 8;
    const ushortT* g5 = Al_g + (size_t)(rowBase + 128 + rl) * K + ks * 8;
    const int d8 = tid * 8;
#define STG(src, dstoff, buf, k0) gload_lds16((src) + (k0), &lds[buf][(dstoff) + d8])

    // fragment addressing
    const int warpM = wid >> 2, warpN = wid & 3;   // 2 x 4 waves, per-wave 128x32 of C
    const int frow = lane & 15, fk = lane >> 4;
    const int pslot = fk ^ ((frow >> 1) & 3);
    const int aoff = (warpM * 128 + frow) * 32 + pslot * 8;
    const int boff = (warpN * 32 + frow) * 32 + pslot * 8;

    f32_4 acc[8][2];
#pragma unroll
    for (int i = 0; i < 8; ++i) { acc[i][0] = f32_4{0,0,0,0}; acc[i][1] = f32_4{0,0,0,0}; }

    // prologue: stage tile 0 into buf 0
    STG(g0, 0, 0, 0); STG(g1, 4096, 0, 0); STG(g2, 16384, 0, 0);
    STG(g3, 20480, 0, 0); STG(g4, 8192, 0, 0); STG(g5, 12288, 0, 0);

    const int nt = K >> 5;
    for (int t = 0; t < nt; ++t) {
        const ushortT* lb = lds[t & 1];
        const int nb = (t & 1) ^ 1;
        const int nk = (t + 1) << 5;
        const bool more = (t + 1) < nt;
        bf16_8 ah[8], bh[2], bl[2], al[8];
        // ---------- P0: hi*hi ----------
        if (more) {
            STG(g0, 0, nb, nk); STG(g1, 4096, nb, nk);
            asm volatile("s_waitcnt vmcnt(5)" ::: "memory");
        } else {
            asm volatile("s_waitcnt vmcnt(3)" ::: "memory");
        }
        asm volatile("s_barrier" ::: "memory");
#pragma unroll
        for (int i = 0; i < 8; ++i) ah[i] = *reinterpret_cast<const bf16_8*>(&lb[aoff + i * 512]);
        bh[0] = *reinterpret_cast<const bf16_8*>(&lb[16384 + boff]);
        bh[1] = *reinterpret_cast<const bf16_8*>(&lb[16384 + boff + 512]);
        __builtin_amdgcn_s_setprio(1);
#pragma unroll
        for (int i = 0; i < 8; ++i) {
            acc[i][0] = MFMA16(ah[i], bh[0], acc[i][0], 0, 0, 0);
            acc[i][1] = MFMA16(ah[i], bh[1], acc[i][1], 0, 0, 0);
        }
        __builtin_amdgcn_s_setprio(0);
        // ---------- P1: hi*lo ----------
        if (more) {
            STG(g2, 16384, nb, nk); STG(g3, 20480, nb, nk);
            asm volatile("s_waitcnt vmcnt(6)" ::: "memory");
        } else {
            asm volatile("s_waitcnt vmcnt(2)" ::: "memory");
        }
        asm volatile("s_barrier" ::: "memory");
        bl[0] = *reinterpret_cast<const bf16_8*>(&lb[20480 + boff]);
        bl[1] = *reinterpret_cast<const bf16_8*>(&lb[20480 + boff + 512]);
        __builtin_amdgcn_s_setprio(1);
#pragma unroll
        for (int i = 0; i < 8; ++i) {
            acc[i][0] = MFMA16(ah[i], bl[0], acc[i][0], 0, 0, 0);
            acc[i][1] = MFMA16(ah[i], bl[1], acc[i][1], 0, 0, 0);
        }
        __builtin_amdgcn_s_setprio(0);
        // ---------- P2: lo*hi ----------
        if (more) {
            STG(g4, 8192, nb, nk); STG(g5, 12288, nb, nk);
            asm volatile("s_waitcnt vmcnt(6)" ::: "memory");
        } else {
            asm volatile("s_waitcnt vmcnt(0)" ::: "memory");
        }
        asm volatile("s_barrier" ::: "memory");
#pragma unroll
        for (int i = 0; i < 8; ++i) al[i] = *reinterpret_cast<const bf16_8*>(&lb[8192 + aoff + i * 512]);
        __builtin_amdgcn_s_setprio(1);
#pragma unroll
        for (int i = 0; i < 8; ++i) {
            acc[i][0] = MFMA16(al[i], bh[0], acc[i][0], 0, 0, 0);
            acc[i][1] = MFMA16(al[i], bh[1], acc[i][1], 0, 0, 0);
        }
        __builtin_amdgcn_s_setprio(0);
        // buffer-swap guard: reads of lds[t&1] must complete before next tile overwrites it
        asm volatile("s_waitcnt lgkmcnt(0)" ::: "memory");
        asm volatile("s_barrier" ::: "memory");
    }
#undef STG

    // ---------------- epilogue ----------------
    const int cbase = colBase + warpN * 32 + frow;
    if (OUTMODE == 0) {
        const float bv0 = bias[cbase];
        const float bv1 = bias[cbase + 16];
        const size_t slice = (size_t)(cb * 4 + warpN) * Nrows;
#pragma unroll
        for (int i = 0; i < 8; ++i) {
            const int row0 = rowBase + warpM * 128 + i * 16 + fk * 4;
            float4 sa4 = float4{1.f, 1.f, 1.f, 1.f};
            if (scaleA) sa4 = *reinterpret_cast<const float4*>(&scaleA[row0]);
            float psum[4];
#pragma unroll
            for (int r = 0; r < 4; ++r) {
                const float sa = reinterpret_cast<const float*>(&sa4)[r];
                const int row = row0 + r;
                float y0 = sa * acc[i][0][r] + bv0;
                if (cbase == 0) y0 = 0.f;                 // component-0 of the tangent
                float y1 = sa * acc[i][1][r] + bv1;
                ushortT h0, l0, h1, l1;
                bsplit(y0, h0, l0); bsplit(y1, h1, l1);
                const size_t base = (size_t)row * M;
                outH[base + cbase] = h0; outH[base + cbase + 16] = h1;
                outL[base + cbase] = l0; outL[base + cbase + 16] = l1;
                float ssv = y0 * y0 + y1 * y1;
                ssv += __shfl_xor(ssv, 1, 64); ssv += __shfl_xor(ssv, 2, 64);
                ssv += __shfl_xor(ssv, 4, 64); ssv += __shfl_xor(ssv, 8, 64);
                psum[r] = ssv;
            }
            if (frow == 0) {
#pragma unroll
                for (int r = 0; r < 4; ++r) partials[slice + row0 + r] = psum[r];
            }
        }
    } else {
#pragma unroll
        for (int i = 0; i < 8; ++i) {
            const int row0 = rowBase + warpM * 128 + i * 16 + fk * 4;
            float4 sa4 = float4{1.f, 1.f, 1.f, 1.f};
            if (scaleA) sa4 = *reinterpret_cast<const float4*>(&scaleA[row0]);
#pragma unroll
            for (int r = 0; r < 4; ++r) {
                const float sa = reinterpret_cast<const float*>(&sa4)[r];
                const size_t base = (size_t)(row0 + r) * M;
                outF[base + cbase]      = sa * acc[i][0][r] + bias[cbase];
                outF[base + cbase + 16] = sa * acc[i][1][r] + bias[cbase + 16];
            }
        }
    }
}

// ---------------- final Lorentz chain, rows of 256 ----------------
__global__ void final_kernel(const float* __restrict__ y2buf, const float* __restrict__ z,
                             const float* __restrict__ alpha_p, const float* __restrict__ step_p,
                             float* __restrict__ out, int N) {
    int gw = (blockIdx.x * blockDim.x + threadIdx.x) >> 6;
    int lane = threadIdx.x & 63;
    if (gw >= N) return;
    const bool l0 = (lane == 0);

    float4 yv = reinterpret_cast<const float4*>(y2buf + (size_t)gw * 256)[lane];
    float4 zv = reinterpret_cast<const float4*>(z + (size_t)gw * 256)[lane];
    float z0 = __shfl(zv.x, 0, 64);

    float yx = l0 ? 0.f : yv.x;
    float ss2 = wred(yx * yx + yv.y * yv.y + yv.z * yv.z + yv.w * yv.w);
    float n2 = sqrtf(ss2);
    float s2 = fminf(1.f, MAXN / fmaxf(n2, EPSF));
    float step = 1.f / (1.f + expf(-step_p[0]));
    float k1 = s2 * step;
    float vfx = yx * k1, vfy = yv.y * k1, vfz = yv.z * k1, vfw = yv.w * k1;

    float r2 = wred(vfx * vfx + vfy * vfy + vfz * vfz + vfw * vfw);
    float n = sqrtf(fmaxf(r2, 0.f));
    float sc = fminf(1.f, MAXN / fmaxf(n, EPSF));
    float m = fminf(n, MAXN);
    float ch = coshf(m), sd = sinh_div_f(m);
    float ex = ch * zv.x + sd * sc * vfx;
    float ey = ch * zv.y + sd * sc * vfy;
    float ez = ch * zv.z + sd * sc * vfz;
    float ew = ch * zv.w + sd * sc * vfw;
    float exq = l0 ? 0.f : ex;
    float r3 = wred(exq * exq + ey * ey + ez * ez + ew * ew);
    float u0 = sqrtf(1.f + r3);

    float r4 = wred((l0 ? 0.f : zv.x * ex) + zv.y * ey + zv.z * ez + zv.w * ew);
    float ip = r4 - z0 * u0;
    ip = fminf(ip, -(1.f + EPSF));
    float dd = acoshf(-ip);
    float g = div_sinh_f(dd);
    float a = 1.f / (1.f + expf(-alpha_p[0]));
    float oa = (1.f - a) * g;
    float st0 = oa * (u0 + ip * z0);
    float stx = oa * (ex + ip * zv.x);
    float sty = oa * (ey + ip * zv.y);
    float stz = oa * (ez + ip * zv.z);
    float stw = oa * (ew + ip * zv.w);
    float stxq = l0 ? 0.f : stx;

    float r5 = wred(stxq * stxq + sty * sty + stz * stz + stw * stw);
    float vv2 = r5 - st0 * st0;
    float n5 = sqrtf(fmaxf(vv2, 0.f));
    float s5 = fminf(1.f, MAXN / fmaxf(n5, EPSF));
    float m5 = fminf(n5, MAXN);
    float ch5 = coshf(m5), sd5 = sinh_div_f(m5);
    float fx = ch5 * zv.x + sd5 * s5 * stxq;
    float fy = ch5 * zv.y + sd5 * s5 * sty;
    float fz = ch5 * zv.z + sd5 * s5 * stz;
    float fw = ch5 * zv.w + sd5 * s5 * stw;
    float fxq = l0 ? 0.f : fx;
    float r6 = wred(fxq * fxq + fy * fy + fz * fz + fw * fw);
    float zn0 = sqrtf(1.f + r6);
    if (l0) fx = zn0;

    float4 o;
    o.x = fx; o.y = fy; o.z = fz; o.w = fw;
    reinterpret_cast<float4*>(out + (size_t)gw * 256)[lane] = o;
    reinterpret_cast<float4*>(out + ((size_t)N + gw) * 256)[lane] = zv;
}

extern "C" void kernel_launch(void* const* d_in, const int* in_sizes, int n_in,
                              void* d_out, int out_size, void* d_ws, size_t ws_size,
                              hipStream_t stream) {
    const float* z_h  = (const float*)d_in[0];
    const float* w0   = (const float*)d_in[1];
    const float* b0   = (const float*)d_in[2];
    const float* w1   = (const float*)d_in[3];
    const float* b1   = (const float*)d_in[4];
    const float* w2   = (const float*)d_in[5];
    const float* b2   = (const float*)d_in[6];
    const float* alph = (const float*)d_in[7];
    const float* stps = (const float*)d_in[8];
    float* out = (float*)d_out;

    const int D = 256, H = 1024;
    const int N = in_sizes[0] / D;   // 32768

    // ---- d_out head arena (all dead before final_kernel writes out) ----
    char* arena = (char*)d_out;
    ushortT* w0h = (ushortT*)(arena + 0);              // 512 KB
    ushortT* w0l = (ushortT*)(arena + 524288);
    ushortT* w1h = (ushortT*)(arena + 1048576);        // 2 MB
    ushortT* w1l = (ushortT*)(arena + 3145728);
    ushortT* w2h = (ushortT*)(arena + 5242880);        // 512 KB
    ushortT* w2l = (ushortT*)(arena + 5767168);
    float* partials = (float*)(arena + 6291456);       // 32 * N * 4 = 4 MB
    float* s1 = (float*)(arena + 10485760);            // N * 4
    float* s2 = (float*)(arena + 10616832);            // N * 4
    ushortT* p0h = (ushortT*)(arena + 10747904);       // N*256*2 = 16 MB
    ushortT* p0l = (ushortT*)(arena + 27525120);       // ends 42.25 MB < 64 MB

    // ---- workspace: two N x 1024 plane pairs (exactly 256 MB) ----
    ushortT* paH = (ushortT*)d_ws;
    ushortT* paL = paH + (size_t)N * H;
    ushortT* pbH = paL + (size_t)N * H;
    ushortT* pbL = pbH + (size_t)N * H;
    float* y2F = (float*)d_ws;   // 32 MB, reuses paH head (dead after GEMM1)

    split_kernel<<<(H * D / 4 + 255) / 256, 256, 0, stream>>>(w0, w0h, w0l, H * D / 4);
    split_kernel<<<(H * H / 4 + 255) / 256, 256, 0, stream>>>(w1, w1h, w1l, H * H / 4);
    split_kernel<<<(D * H / 4 + 255) / 256, 256, 0, stream>>>(w2, w2h, w2l, D * H / 4);

    prep_kernel<<<N / 4, 256, 0, stream>>>(z_h, p0h, p0l, N);

    // GEMM0: y0 = prepPlanes @ W0^T + b0 -> planes paH/paL + partials
    gemm_v3<0><<<(N / 256) * (H / 128), 512, 0, stream>>>(
        p0h, p0l, w0h, w0l, b0, nullptr, nullptr, paH, paL, partials, D, H, H / 128, N);
    rowscale_kernel<<<(N + 255) / 256, 256, 0, stream>>>(partials, s1, N, 32);

    // GEMM1: y1 = (s1 * y0planes) @ W1^T + b1 -> planes pbH/pbL + partials
    gemm_v3<0><<<(N / 256) * (H / 128), 512, 0, stream>>>(
        paH, paL, w1h, w1l, b1, s1, nullptr, pbH, pbL, partials, H, H, H / 128, N);
    rowscale_kernel<<<(N + 255) / 256, 256, 0, stream>>>(partials, s2, N, 32);

    // GEMM2: y2 = (s2 * y1planes) @ W2^T + b2 -> f32 (reuses paH head; paH dead)
    gemm_v3<1><<<(N / 256) * (D / 128), 512, 0, stream>>>(
        pbH, pbL, w2h, w2l, b2, s2, y2F, nullptr, nullptr, nullptr, H, D, D / 128, N);

    final_kernel<<<N / 4, 256, 0, stream>>>(y2F, z_h, alph, stps, out, N);
}

// Round 4
// 381.549 us; speedup vs baseline: 3.4141x; 1.1062x over previous
//
#include <hip/hip_runtime.h>
#include <math.h>

#define EPSF 1e-7f
#define MAXN 10.0f

typedef unsigned short ushortT;
typedef __bf16 bf16_8 __attribute__((ext_vector_type(8)));
typedef float f32_4 __attribute__((ext_vector_type(4)));

#define MFMA16 __builtin_amdgcn_mfma_f32_16x16x32_bf16
#define BAR asm volatile("s_barrier" ::: "memory")

__device__ __forceinline__ float sinh_div_f(float d) {
    float ds = fmaxf(d, 1e-6f);
    return (d < 1e-6f) ? 1.0f : sinhf(ds) / ds;
}
__device__ __forceinline__ float div_sinh_f(float d) {
    float ds = fmaxf(d, 1e-6f);
    return (d < 1e-6f) ? 1.0f : ds / sinhf(ds);
}
__device__ __forceinline__ float wred(float v) {
#pragma unroll
    for (int off = 32; off > 0; off >>= 1) v += __shfl_xor(v, off, 64);
    return v;
}
// f32 -> bf16(hi) + bf16(lo), both RNE
__device__ __forceinline__ void bsplit(float x, ushortT& h, ushortT& l) {
    unsigned u = __float_as_uint(x);
    unsigned r = (u + 0x7fffu + ((u >> 16) & 1u)) >> 16;
    h = (ushortT)r;
    float lo = x - __uint_as_float(r << 16);
    unsigned ul = __float_as_uint(lo);
    l = (ushortT)((ul + 0x7fffu + ((ul >> 16) & 1u)) >> 16);
}
__device__ __forceinline__ void gload_lds16(const void* g, void* l) {
    __builtin_amdgcn_global_load_lds(
        (const __attribute__((address_space(1))) unsigned int*)g,
        (__attribute__((address_space(3))) unsigned int*)l, 16, 0, 0);
}

// ---------------- weight split ----------------
__global__ void split_kernel(const float* __restrict__ x, ushortT* __restrict__ hi,
                             ushortT* __restrict__ lo, int n4) {
    int idx = blockIdx.x * blockDim.x + threadIdx.x;
    if (idx >= n4) return;
    float4 v = reinterpret_cast<const float4*>(x)[idx];
    float f[4] = {v.x, v.y, v.z, v.w};
    ushortT hh[4], ll[4];
#pragma unroll
    for (int e = 0; e < 4; ++e) bsplit(f[e], hh[e], ll[e]);
    reinterpret_cast<ushort4*>(hi)[idx] = ushort4{hh[0], hh[1], hh[2], hh[3]};
    reinterpret_cast<ushort4*>(lo)[idx] = ushort4{ll[0], ll[1], ll[2], ll[3]};
}

// ---------------- prep: z_h -> clamped tangent planes (rows of 256) ----------------
__global__ void prep_kernel(const float* __restrict__ z, ushortT* __restrict__ th,
                            ushortT* __restrict__ tl, int N) {
    int gw = (blockIdx.x * blockDim.x + threadIdx.x) >> 6;
    int lane = threadIdx.x & 63;
    if (gw >= N) return;
    float4 zv = reinterpret_cast<const float4*>(z + (size_t)gw * 256)[lane];
    float z0 = __shfl(zv.x, 0, 64);
    float x0 = fmaxf(z0, 1.f + EPSF);
    float d = acoshf(x0);
    float f = div_sinh_f(d);
    float vx = (lane == 0) ? 0.f : zv.x * f;
    float vy = zv.y * f, vz = zv.z * f, vw = zv.w * f;
    float ss = wred(vx * vx + vy * vy + vz * vz + vw * vw);
    float n = sqrtf(ss);
    float s = fminf(1.f, MAXN / fmaxf(n, EPSF));
    float o[4] = {vx * s, vy * s, vz * s, vw * s};
    ushortT hh[4], ll[4];
#pragma unroll
    for (int e = 0; e < 4; ++e) bsplit(o[e], hh[e], ll[e]);
    reinterpret_cast<ushort4*>(th + (size_t)gw * 256)[lane] = ushort4{hh[0], hh[1], hh[2], hh[3]};
    reinterpret_cast<ushort4*>(tl + (size_t)gw * 256)[lane] = ushort4{ll[0], ll[1], ll[2], ll[3]};
}

// ---------------- row scale from partial sumsq ----------------
__global__ void rowscale_kernel(const float* __restrict__ partials, float* __restrict__ scale,
                                int N, int nSlices) {
    int r = blockIdx.x * blockDim.x + threadIdx.x;
    if (r >= N) return;
    float s = 0.f;
    for (int k = 0; k < nSlices; ++k) s += partials[(size_t)k * N + r];
    float n = sqrtf(s);
    scale[r] = fminf(1.f, MAXN / fmaxf(n, EPSF));
}

// ---------------- 6-phase 256-wide split-bf16 MFMA GEMM ----------------
// C[N x M] = (sA_r * A) @ W^T + bias. A planes [N][K], W planes [M][K].
// BM = IM*32 (256 or 128), BN = 256, BK = 32. 8 waves as 2(M) x 4(N); per-wave IM x 4 frags.
// 3-term split: hi*hi + hi*lo + lo*hi. 6 phases/tile, 16(8) MFMA each; stage rounds of next
// tile spread over phases 0-3; loads stay in flight across phase barriers; vmcnt(0) only at
// tile end. LDS dest linear, source pre-swizzled (slot ^= (row>>1)&3) -> conflict-free reads.
template<int OUTMODE, int IM>
__global__ __launch_bounds__(512, 2) void gemm_v4(
    const ushortT* __restrict__ Ah_g, const ushortT* __restrict__ Al_g,
    const ushortT* __restrict__ Wh_g, const ushortT* __restrict__ Wl_g,
    const float* __restrict__ bias, const float* __restrict__ scaleA,
    float* __restrict__ outF, ushortT* __restrict__ outH, ushortT* __restrict__ outL,
    float* __restrict__ partials, int K, int M, int nColBlk, int Nrows)
{
    constexpr int BM = IM * 32;
    constexpr int AS = BM * 32;        // per-plane A elems per buffer
    constexpr int BS = 256 * 32;       // per-plane B elems
    constexpr int BUF = 2 * AS + 2 * BS;
    constexpr int HM = IM / 2;
    __shared__ __align__(16) ushortT lds[2 * BUF];

    const int tid = threadIdx.x;
    const int wid = tid >> 6, lane = tid & 63;
    const int nwg = gridDim.x;
    const int swz = ((int)blockIdx.x & 7) * (nwg >> 3) + ((int)blockIdx.x >> 3);
    const int rb = swz / nColBlk, cb = swz % nColBlk;
    const int rowBase = rb * BM, colBase = cb * 256;

    // staging addressing: one round = 512 thr x 16B = 128 rows x 32 elems, LDS dest linear
    const int rl = tid >> 2;
    const int ks = (tid & 3) ^ ((rl >> 1) & 3);   // pre-swizzled source slot
    const int d8 = tid * 8;
    const ushortT* gAh0 = Ah_g + (size_t)(rowBase + rl) * K + ks * 8;
    const ushortT* gAl0 = Al_g + (size_t)(rowBase + rl) * K + ks * 8;
    const ushortT* gAh1 = Ah_g + (size_t)(rowBase + 128 + rl) * K + ks * 8;  // IM==8 only
    const ushortT* gAl1 = Al_g + (size_t)(rowBase + 128 + rl) * K + ks * 8;
    const ushortT* gBh0 = Wh_g + (size_t)(colBase + rl) * K + ks * 8;
    const ushortT* gBh1 = Wh_g + (size_t)(colBase + 128 + rl) * K + ks * 8;
    const ushortT* gBl0 = Wl_g + (size_t)(colBase + rl) * K + ks * 8;
    const ushortT* gBl1 = Wl_g + (size_t)(colBase + 128 + rl) * K + ks * 8;
#define STG(p, dst, nbo, nk) gload_lds16((p) + (nk), &lds[(nbo) + (dst) + d8])

    // fragment addressing
    const int warpM = wid >> 2, warpN = wid & 3;     // 2 x 4
    const int frow = lane & 15, fk = lane >> 4;
    const int pslot8 = (fk ^ ((frow >> 1) & 3)) * 8;
    const int aoff = (warpM * (IM * 16) + frow) * 32 + pslot8;   // + i*512
    const int boff = (warpN * 64 + frow) * 32 + pslot8;          // + j*512

    f32_4 acc[IM][4];
#pragma unroll
    for (int i = 0; i < IM; ++i)
#pragma unroll
        for (int j = 0; j < 4; ++j) acc[i][j] = f32_4{0.f, 0.f, 0.f, 0.f};

    // prologue: stage tile 0 into buffer 0
    STG(gAh0, 0, 0, 0);
    if constexpr (IM == 8) STG(gAh1, 4096, 0, 0);
    STG(gAl0, AS, 0, 0);
    if constexpr (IM == 8) STG(gAl1, AS + 4096, 0, 0);
    STG(gBh0, 2 * AS, 0, 0); STG(gBh1, 2 * AS + 4096, 0, 0);
    STG(gBl0, 2 * AS + BS, 0, 0); STG(gBl1, 2 * AS + BS + 4096, 0, 0);
    asm volatile("s_waitcnt vmcnt(0)" ::: "memory");
    BAR;

    const int nt = K >> 5;
    for (int t = 0; t < nt; ++t) {
        const ushortT* lb = &lds[(t & 1) * BUF];
        const int nbo = ((t & 1) ^ 1) * BUF;
        const int nk = (t + 1) << 5;
        const bool more = (t + 1) < nt;
        bf16_8 ah[IM], bh[4], bl[4], alx[HM];

        // ---- P0: read ah[0..HM-1], bh[0..3]; stage Ah; MFMA hi*hi (h=0) ----
#pragma unroll
        for (int i = 0; i < HM; ++i) ah[i] = *reinterpret_cast<const bf16_8*>(&lb[aoff + i * 512]);
#pragma unroll
        for (int j = 0; j < 4; ++j) bh[j] = *reinterpret_cast<const bf16_8*>(&lb[2 * AS + boff + j * 512]);
        if (more) { STG(gAh0, 0, nbo, nk); if constexpr (IM == 8) STG(gAh1, 4096, nbo, nk); }
        BAR;
        __builtin_amdgcn_s_setprio(1);
#pragma unroll
        for (int i = 0; i < HM; ++i)
#pragma unroll
            for (int j = 0; j < 4; ++j) acc[i][j] = MFMA16(ah[i], bh[j], acc[i][j], 0, 0, 0);
        __builtin_amdgcn_s_setprio(0);

        // ---- P1: read ah[HM..IM-1]; stage Al; MFMA hi*hi (h=1) ----
#pragma unroll
        for (int i = HM; i < IM; ++i) ah[i] = *reinterpret_cast<const bf16_8*>(&lb[aoff + i * 512]);
        if (more) { STG(gAl0, AS, nbo, nk); if constexpr (IM == 8) STG(gAl1, AS + 4096, nbo, nk); }
        BAR;
        __builtin_amdgcn_s_setprio(1);
#pragma unroll
        for (int i = HM; i < IM; ++i)
#pragma unroll
            for (int j = 0; j < 4; ++j) acc[i][j] = MFMA16(ah[i], bh[j], acc[i][j], 0, 0, 0);
        __builtin_amdgcn_s_setprio(0);

        // ---- P2: read bl[0..3]; stage Bh; MFMA hi*lo (h=0) ----
#pragma unroll
        for (int j = 0; j < 4; ++j) bl[j] = *reinterpret_cast<const bf16_8*>(&lb[2 * AS + BS + boff + j * 512]);
        if (more) { STG(gBh0, 2 * AS, nbo, nk); STG(gBh1, 2 * AS + 4096, nbo, nk); }
        BAR;
        __builtin_amdgcn_s_setprio(1);
#pragma unroll
        for (int i = 0; i < HM; ++i)
#pragma unroll
            for (int j = 0; j < 4; ++j) acc[i][j] = MFMA16(ah[i], bl[j], acc[i][j], 0, 0, 0);
        __builtin_amdgcn_s_setprio(0);

        // ---- P3: stage Bl; MFMA hi*lo (h=1) ----
        if (more) { STG(gBl0, 2 * AS + BS, nbo, nk); STG(gBl1, 2 * AS + BS + 4096, nbo, nk); }
        BAR;
        __builtin_amdgcn_s_setprio(1);
#pragma unroll
        for (int i = HM; i < IM; ++i)
#pragma unroll
            for (int j = 0; j < 4; ++j) acc[i][j] = MFMA16(ah[i], bl[j], acc[i][j], 0, 0, 0);
        __builtin_amdgcn_s_setprio(0);

        // ---- P4: read al (h=0); MFMA lo*hi (h=0) ----
#pragma unroll
        for (int i = 0; i < HM; ++i) alx[i] = *reinterpret_cast<const bf16_8*>(&lb[AS + aoff + i * 512]);
        BAR;
        __builtin_amdgcn_s_setprio(1);
#pragma unroll
        for (int i = 0; i < HM; ++i)
#pragma unroll
            for (int j = 0; j < 4; ++j) acc[i][j] = MFMA16(alx[i], bh[j], acc[i][j], 0, 0, 0);
        __builtin_amdgcn_s_setprio(0);

        // ---- P5: read al (h=1); MFMA lo*hi (h=1) ----
#pragma unroll
        for (int i = 0; i < HM; ++i) alx[i] = *reinterpret_cast<const bf16_8*>(&lb[AS + aoff + (HM + i) * 512]);
        BAR;
        __builtin_amdgcn_s_setprio(1);
#pragma unroll
        for (int i = 0; i < HM; ++i)
#pragma unroll
            for (int j = 0; j < 4; ++j) acc[HM + i][j] = MFMA16(alx[i], bh[j], acc[HM + i][j], 0, 0, 0);
        __builtin_amdgcn_s_setprio(0);

        // ---- tile end: next tile's staged data must be resident before anyone reads it ----
        asm volatile("s_waitcnt vmcnt(0)" ::: "memory");
        BAR;
    }
#undef STG

    // ---------------- epilogue ----------------
    const int cbase = colBase + warpN * 64 + frow;
    if (OUTMODE == 0) {
        float bv[4];
#pragma unroll
        for (int j = 0; j < 4; ++j) bv[j] = bias[cbase + j * 16];
        const size_t slice = (size_t)(cb * 4 + warpN) * Nrows;
#pragma unroll
        for (int i = 0; i < IM; ++i) {
            const int row0 = rowBase + warpM * (IM * 16) + i * 16 + fk * 4;
            float4 sa4 = float4{1.f, 1.f, 1.f, 1.f};
            if (scaleA) sa4 = *reinterpret_cast<const float4*>(&scaleA[row0]);
            float psum[4];
#pragma unroll
            for (int r = 0; r < 4; ++r) {
                const float sa = reinterpret_cast<const float*>(&sa4)[r];
                const int row = row0 + r;
                const size_t base = (size_t)row * M;
                float ssv = 0.f;
#pragma unroll
                for (int j = 0; j < 4; ++j) {
                    float y = sa * acc[i][j][r] + bv[j];
                    if (j == 0 && cbase == 0) y = 0.f;     // tangent component 0
                    ushortT h, l;
                    bsplit(y, h, l);
                    outH[base + cbase + j * 16] = h;
                    outL[base + cbase + j * 16] = l;
                    ssv += y * y;
                }
                ssv += __shfl_xor(ssv, 1, 64); ssv += __shfl_xor(ssv, 2, 64);
                ssv += __shfl_xor(ssv, 4, 64); ssv += __shfl_xor(ssv, 8, 64);
                psum[r] = ssv;
            }
            if (frow == 0) {
#pragma unroll
                for (int r = 0; r < 4; ++r) partials[slice + row0 + r] = psum[r];
            }
        }
    } else {
#pragma unroll
        for (int i = 0; i < IM; ++i) {
            const int row0 = rowBase + warpM * (IM * 16) + i * 16 + fk * 4;
            float4 sa4 = float4{1.f, 1.f, 1.f, 1.f};
            if (scaleA) sa4 = *reinterpret_cast<const float4*>(&scaleA[row0]);
#pragma unroll
            for (int r = 0; r < 4; ++r) {
                const float sa = reinterpret_cast<const float*>(&sa4)[r];
                const size_t base = (size_t)(row0 + r) * M;
#pragma unroll
                for (int j = 0; j < 4; ++j)
                    outF[base + cbase + j * 16] = sa * acc[i][j][r] + bias[cbase + j * 16];
            }
        }
    }
}

// ---------------- final Lorentz chain, rows of 256 ----------------
__global__ void final_kernel(const float* __restrict__ y2buf, const float* __restrict__ z,
                             const float* __restrict__ alpha_p, const float* __restrict__ step_p,
                             float* __restrict__ out, int N) {
    int gw = (blockIdx.x * blockDim.x + threadIdx.x) >> 6;
    int lane = threadIdx.x & 63;
    if (gw >= N) return;
    const bool l0 = (lane == 0);

    float4 yv = reinterpret_cast<const float4*>(y2buf + (size_t)gw * 256)[lane];
    float4 zv = reinterpret_cast<const float4*>(z + (size_t)gw * 256)[lane];
    float z0 = __shfl(zv.x, 0, 64);

    float yx = l0 ? 0.f : yv.x;
    float ss2 = wred(yx * yx + yv.y * yv.y + yv.z * yv.z + yv.w * yv.w);
    float n2 = sqrtf(ss2);
    float s2 = fminf(1.f, MAXN / fmaxf(n2, EPSF));
    float step = 1.f / (1.f + expf(-step_p[0]));
    float k1 = s2 * step;
    float vfx = yx * k1, vfy = yv.y * k1, vfz = yv.z * k1, vfw = yv.w * k1;

    float r2 = wred(vfx * vfx + vfy * vfy + vfz * vfz + vfw * vfw);
    float n = sqrtf(fmaxf(r2, 0.f));
    float sc = fminf(1.f, MAXN / fmaxf(n, EPSF));
    float m = fminf(n, MAXN);
    float ch = coshf(m), sd = sinh_div_f(m);
    float ex = ch * zv.x + sd * sc * vfx;
    float ey = ch * zv.y + sd * sc * vfy;
    float ez = ch * zv.z + sd * sc * vfz;
    float ew = ch * zv.w + sd * sc * vfw;
    float exq = l0 ? 0.f : ex;
    float r3 = wred(exq * exq + ey * ey + ez * ez + ew * ew);
    float u0 = sqrtf(1.f + r3);

    float r4 = wred((l0 ? 0.f : zv.x * ex) + zv.y * ey + zv.z * ez + zv.w * ew);
    float ip = r4 - z0 * u0;
    ip = fminf(ip, -(1.f + EPSF));
    float dd = acoshf(-ip);
    float g = div_sinh_f(dd);
    float a = 1.f / (1.f + expf(-alpha_p[0]));
    float oa = (1.f - a) * g;
    float st0 = oa * (u0 + ip * z0);
    float stx = oa * (ex + ip * zv.x);
    float sty = oa * (ey + ip * zv.y);
    float stz = oa * (ez + ip * zv.z);
    float stw = oa * (ew + ip * zv.w);
    float stxq = l0 ? 0.f : stx;

    float r5 = wred(stxq * stxq + sty * sty + stz * stz + stw * stw);
    float vv2 = r5 - st0 * st0;
    float n5 = sqrtf(fmaxf(vv2, 0.f));
    float s5 = fminf(1.f, MAXN / fmaxf(n5, EPSF));
    float m5 = fminf(n5, MAXN);
    float ch5 = coshf(m5), sd5 = sinh_div_f(m5);
    float fx = ch5 * zv.x + sd5 * s5 * stxq;
    float fy = ch5 * zv.y + sd5 * s5 * sty;
    float fz = ch5 * zv.z + sd5 * s5 * stz;
    float fw = ch5 * zv.w + sd5 * s5 * stw;
    float fxq = l0 ? 0.f : fx;
    float r6 = wred(fxq * fxq + fy * fy + fz * fz + fw * fw);
    float zn0 = sqrtf(1.f + r6);
    if (l0) fx = zn0;

    float4 o;
    o.x = fx; o.y = fy; o.z = fz; o.w = fw;
    reinterpret_cast<float4*>(out + (size_t)gw * 256)[lane] = o;
    reinterpret_cast<float4*>(out + ((size_t)N + gw) * 256)[lane] = zv;
}

extern "C" void kernel_launch(void* const* d_in, const int* in_sizes, int n_in,
                              void* d_out, int out_size, void* d_ws, size_t ws_size,
                              hipStream_t stream) {
    const float* z_h  = (const float*)d_in[0];
    const float* w0   = (const float*)d_in[1];
    const float* b0   = (const float*)d_in[2];
    const float* w1   = (const float*)d_in[3];
    const float* b1   = (const float*)d_in[4];
    const float* w2   = (const float*)d_in[5];
    const float* b2   = (const float*)d_in[6];
    const float* alph = (const float*)d_in[7];
    const float* stps = (const float*)d_in[8];
    float* out = (float*)d_out;

    const int D = 256, H = 1024;
    const int N = in_sizes[0] / D;   // 32768

    // ---- d_out head arena (all dead before final_kernel writes out) ----
    char* arena = (char*)d_out;
    ushortT* w0h = (ushortT*)(arena + 0);              // 512 KB
    ushortT* w0l = (ushortT*)(arena + 524288);
    ushortT* w1h = (ushortT*)(arena + 1048576);        // 2 MB
    ushortT* w1l = (ushortT*)(arena + 3145728);
    ushortT* w2h = (ushortT*)(arena + 5242880);        // 512 KB
    ushortT* w2l = (ushortT*)(arena + 5767168);
    float* partials = (float*)(arena + 6291456);       // 16 * N * 4 = 2 MB
    float* s1 = (float*)(arena + 10485760);            // N * 4
    float* s2 = (float*)(arena + 10616832);            // N * 4
    ushortT* p0h = (ushortT*)(arena + 10747904);       // N*256*2 = 16 MB
    ushortT* p0l = (ushortT*)(arena + 27525120);       // ends 42.25 MB < 64 MB

    // ---- workspace: two N x 1024 plane pairs (exactly 256 MB) ----
    ushortT* paH = (ushortT*)d_ws;
    ushortT* paL = paH + (size_t)N * H;
    ushortT* pbH = paL + (size_t)N * H;
    ushortT* pbL = pbH + (size_t)N * H;
    float* y2F = (float*)d_ws;   // 32 MB, reuses paH head (dead after GEMM1)

    split_kernel<<<(H * D / 4 + 255) / 256, 256, 0, stream>>>(w0, w0h, w0l, H * D / 4);
    split_kernel<<<(H * H / 4 + 255) / 256, 256, 0, stream>>>(w1, w1h, w1l, H * H / 4);
    split_kernel<<<(D * H / 4 + 255) / 256, 256, 0, stream>>>(w2, w2h, w2l, D * H / 4);

    prep_kernel<<<N / 4, 256, 0, stream>>>(z_h, p0h, p0l, N);

    // GEMM0: y0 = prepPlanes @ W0^T + b0 -> planes paH/paL + partials (16 slices)
    gemm_v4<0, 8><<<(N / 256) * (H / 256), 512, 0, stream>>>(
        p0h, p0l, w0h, w0l, b0, nullptr, nullptr, paH, paL, partials, D, H, H / 256, N);
    rowscale_kernel<<<(N + 255) / 256, 256, 0, stream>>>(partials, s1, N, 16);

    // GEMM1: y1 = (s1 * y0planes) @ W1^T + b1 -> planes pbH/pbL + partials
    gemm_v4<0, 8><<<(N / 256) * (H / 256), 512, 0, stream>>>(
        paH, paL, w1h, w1l, b1, s1, nullptr, pbH, pbL, partials, H, H, H / 256, N);
    rowscale_kernel<<<(N + 255) / 256, 256, 0, stream>>>(partials, s2, N, 16);

    // GEMM2: y2 = (s2 * y1planes) @ W2^T + b2 -> f32 (BM=128 for full CU coverage)
    gemm_v4<1, 4><<<(N / 128) * (D / 256), 512, 0, stream>>>(
        pbH, pbL, w2h, w2l, b2, s2, y2F, nullptr, nullptr, nullptr, H, D, D / 256, N);

    final_kernel<<<N / 4, 256, 0, stream>>>(y2F, z_h, alph, stps, out, N);
}